// Round 5
// baseline (241.497 us; speedup 1.0000x reference)
//
#include <hip/hip_runtime.h>
#include <hip/hip_bf16.h>

typedef __bf16 bf16_t;
typedef __bf16 bf16x8 __attribute__((ext_vector_type(8)));
typedef __bf16 bf16x4 __attribute__((ext_vector_type(4)));
typedef short short4v __attribute__((ext_vector_type(4)));
typedef float f32x4 __attribute__((ext_vector_type(4)));

static_assert(sizeof(bf16x8) == 16, "bf16x8 must be 16B");

// Problem constants
#define BB 2
#define SS 2048
#define DD 512
#define HH 8
#define DH 64
// HID == 512; head block = contiguous [2048,64] at (b*8+h)*131072

// ------------- prep: z=0..2 cast q/k/v f32->bf16; z=3 transpose+cast weights -------------
__global__ void prep(const float* __restrict__ q, const float* __restrict__ k,
                     const float* __restrict__ v, const float* __restrict__ w0,
                     const float* __restrict__ w1, const float* __restrict__ w2,
                     const float* __restrict__ w3, bf16_t* __restrict__ qkvb,
                     bf16_t* __restrict__ wt, int n) {
  const int tid = threadIdx.x;
  if (blockIdx.z < 3) {
    const float* src = (blockIdx.z == 0) ? q : (blockIdx.z == 1) ? k : v;
    bf16_t* out = qkvb + (size_t)blockIdx.z * n;
    int i = (blockIdx.x * 256 + tid) * 8;
    if (i >= n) return;
    const float4* s4 = (const float4*)(src + i);
    float4 a = s4[0], b = s4[1];
    bf16x8 o;
    o[0] = (bf16_t)a.x; o[1] = (bf16_t)a.y; o[2] = (bf16_t)a.z; o[3] = (bf16_t)a.w;
    o[4] = (bf16_t)b.x; o[5] = (bf16_t)b.y; o[6] = (bf16_t)b.z; o[7] = (bf16_t)b.w;
    *(bf16x8*)(out + i) = o;
  } else {
    // transpose+cast: Wt[nn][kk] = (bf16)W[kk][nn]
    __shared__ float tile[32][33];
    const int x = blockIdx.x;                  // 0..1023
    const int wsel = x >> 8;
    const int nb = ((x >> 4) & 15) * 32, kb = (x & 15) * 32;
    const int tx = tid & 31, ty = tid >> 5;    // (32,8)
    const float* W = (wsel == 0) ? w0 : (wsel == 1) ? w1 : (wsel == 2) ? w2 : w3;
    bf16_t* out = wt + (size_t)wsel * 512 * 512;
#pragma unroll
    for (int i = 0; i < 4; i++)
      tile[ty + i * 8][tx] = W[(size_t)(kb + ty + i * 8) * 512 + nb + tx];
    __syncthreads();
#pragma unroll
    for (int i = 0; i < 4; i++)
      out[(size_t)(nb + ty + i * 8) * 512 + kb + tx] = (bf16_t)tile[tx][ty + i * 8];
  }
}

// ------------- GEMM: C[M,N] = A[M,K] @ Bt[N,K]^T + bias[N] -------------
// 128x128 tile, BK=64, 256 thr (4 waves 2x2), global_load_lds(16B), dbuf LDS.
template <typename OutT>
__global__ __launch_bounds__(256) void gemm_bt(
    const bf16_t* __restrict__ Abase, const bf16_t* __restrict__ Btbase,
    const float* __restrict__ bias0, const float* __restrict__ bias1,
    const float* __restrict__ bias2, OutT* __restrict__ Cbase,
    int M, int N, int K, long Az, long Bz, long Cz) {
  const bf16_t* A  = Abase + (size_t)blockIdx.z * Az;
  const bf16_t* Bt = Btbase + (size_t)blockIdx.z * Bz;
  const float* bias = (blockIdx.z == 0) ? bias0 : (blockIdx.z == 1) ? bias1 : bias2;
  OutT* C = Cbase + (size_t)blockIdx.z * Cz;

  __shared__ bf16_t As[2][128 * 64];
  __shared__ bf16_t Bs[2][128 * 64];

  const int tid = threadIdx.x, w = tid >> 6, l = tid & 63;
  const int bm = blockIdx.y, bn = blockIdx.x;
  const int wm = (w >> 1) * 64, wn = (w & 1) * 64;
  const int lr = l & 15, lg = l >> 4;

  f32x4 acc[4][4] = {};

  auto stage = [&](int buf, int kt) {
#pragma unroll
    for (int j = 0; j < 4; j++) {
      int lin = (j * 4 + w) * 64 + l;       // 16B-chunk index 0..1023
      int row = lin >> 3, cc = lin & 7;
      const bf16_t* g = A + (size_t)(bm * 128 + row) * K + kt * 64 + cc * 8;
      __builtin_amdgcn_global_load_lds(
          (const __attribute__((address_space(1))) void*)g,
          (__attribute__((address_space(3))) void*)(&As[buf][(j * 4 + w) * 512]), 16, 0, 0);
    }
#pragma unroll
    for (int j = 0; j < 4; j++) {
      int lin = (j * 4 + w) * 64 + l;
      int row = lin >> 3, cc = lin & 7;
      const bf16_t* g = Bt + (size_t)(bn * 128 + row) * K + kt * 64 + cc * 8;
      __builtin_amdgcn_global_load_lds(
          (const __attribute__((address_space(1))) void*)g,
          (__attribute__((address_space(3))) void*)(&Bs[buf][(j * 4 + w) * 512]), 16, 0, 0);
    }
  };

  stage(0, 0);
  const int KT = K >> 6;
  for (int kt = 0; kt < KT; kt++) {
    __syncthreads();                         // drains vmcnt -> buf[kt&1] ready
    if (kt + 1 < KT) stage((kt + 1) & 1, kt + 1);
    const bf16_t* as = As[kt & 1];
    const bf16_t* bs = Bs[kt & 1];
#pragma unroll
    for (int kc = 0; kc < 2; kc++) {
      bf16x8 a[4], b[4];
#pragma unroll
      for (int i = 0; i < 4; i++)
        a[i] = *(const bf16x8*)(as + (wm + i * 16 + lr) * 64 + kc * 32 + lg * 8);
#pragma unroll
      for (int i = 0; i < 4; i++)
        b[i] = *(const bf16x8*)(bs + (wn + i * 16 + lr) * 64 + kc * 32 + lg * 8);
#pragma unroll
      for (int i = 0; i < 4; i++)
#pragma unroll
        for (int j = 0; j < 4; j++)
          acc[i][j] = __builtin_amdgcn_mfma_f32_16x16x32_bf16(a[i], b[j], acc[i][j], 0, 0, 0);
    }
  }

  // epilogue: C row = (lane>>4)*4+reg, col = lane&15 (verified m89/m91 layout)
  const int row0 = bm * 128 + wm, col0 = bn * 128 + wn;
#pragma unroll
  for (int j = 0; j < 4; j++) {
    int col = col0 + j * 16 + lr;
    float bv = bias[col];
#pragma unroll
    for (int i = 0; i < 4; i++) {
      int row = row0 + i * 16 + lg * 4;
#pragma unroll
      for (int r = 0; r < 4; r++) {
        float vv = acc[i][j][r] + bv;
        C[(size_t)(row + r) * N + col] = (OutT)vv;
      }
    }
  }
}

// ------------- flash attention, KV-split x2 + fused last-block combine -------------
// grid 1024 (1D): id bits -> bh low3 (XCD-affinity), bh hi, qt, half.
// Each block: QBLK=64 (4 waves x 16 q-rows), 16 KV-tiles (half the range).
// Swapped QK^T (S^T = mfma(K,Q)); in-lane online softmax with defer-max;
// PV from registers via 16x16x16 MFMA. LDS: exactly 32KB, T2 XOR-swizzled
// [64][64] K and V^T tiles (no pad), double-buffered.
// The LAST block of each (qt,bh) pair merges both halves and writes ctx.
__global__ __launch_bounds__(256) void attn_flash(const bf16_t* __restrict__ qp,
                                                  const bf16_t* __restrict__ kp,
                                                  const bf16_t* __restrict__ vp,
                                                  float* __restrict__ Opart,
                                                  float* __restrict__ mlpart,
                                                  int* __restrict__ flags,
                                                  bf16_t* __restrict__ ctx) {
  const int id = blockIdx.x;
  const int bh = (id & 7) | (((id >> 3) & 1) << 3);  // blocks of one head share an XCD
  const int qt = (id >> 4) & 31;
  const int half = id >> 9;
  const int gid = (qt << 4) | bh;
  const int pidx = gid * 2 + half;

  const int tid = threadIdx.x, w = tid >> 6, l = tid & 63;
  const int lr = l & 15, lg = l >> 4;
  const size_t hb = (size_t)bh * (SS * DH);        // contiguous [2048,64] head block
  const bf16_t* Q = qp + hb;
  const bf16_t* Kh = kp + hb;
  const bf16_t* Vh = vp + hb;

  // 32KB: Ks [2][64 kv][64 d] at 0, Vt [2][64 d][64 kv] at 16384.
  // byte(row, c) = row*128 + (c ^ ((row&7)<<4))  -- T2 XOR swizzle
  __shared__ __align__(16) unsigned char smem[32768];

  const int qr0 = qt * 64 + w * 16;

  // Q fragment (B-operand: col=lr, k=lg*8+j) held for the whole kernel
  bf16x8 aq[2];
#pragma unroll
  for (int kc = 0; kc < 2; kc++)
    aq[kc] = *(const bf16x8*)(Q + (size_t)(qr0 + lr) * DH + kc * 32 + lg * 8);

  f32x4 o[4] = {};                    // O^T[d = n*16+lg*4+r][q = lr]
  float m_run = -1e30f, l_run = 0.f;  // per-lane scalars (row q = lr)

  // fixed per-thread staging coordinates (chunks of 8 bf16)
  const int c0 = tid, c1 = 256 + tid;
  const int kr0 = c0 >> 3, kq0 = c0 & 7;
  const int kr1 = c1 >> 3, kq1 = c1 & 7;
  const int vk0 = c0 & 63, vd0 = (c0 >> 6) & 7;
  const int vk1 = c1 & 63, vd1 = (c1 >> 6) & 7;

  bf16x8 kreg0, kreg1, vreg0, vreg1;
  auto load_g = [&](int it) {                       // it = global KV-tile index
    const size_t kv0 = (size_t)it * 64;
    kreg0 = *(const bf16x8*)(Kh + (kv0 + kr0) * DH + kq0 * 8);
    kreg1 = *(const bf16x8*)(Kh + (kv0 + kr1) * DH + kq1 * 8);
    vreg0 = *(const bf16x8*)(Vh + (kv0 + vk0) * DH + vd0 * 8);
    vreg1 = *(const bf16x8*)(Vh + (kv0 + vk1) * DH + vd1 * 8);
  };
  auto write_lds = [&](int buf) {
    unsigned char* ks = smem + buf * 8192;
    unsigned char* vt = smem + 16384 + buf * 8192;
    *(bf16x8*)(ks + kr0 * 128 + ((kq0 * 16) ^ ((kr0 & 7) << 4))) = kreg0;
    *(bf16x8*)(ks + kr1 * 128 + ((kq1 * 16) ^ ((kr1 & 7) << 4))) = kreg1;
#pragma unroll
    for (int j = 0; j < 8; j++) {
      int d0 = vd0 * 8 + j;
      *(bf16_t*)(vt + d0 * 128 + ((vk0 * 2) ^ ((d0 & 7) << 4))) = vreg0[j];
    }
#pragma unroll
    for (int j = 0; j < 8; j++) {
      int d1 = vd1 * 8 + j;
      *(bf16_t*)(vt + d1 * 128 + ((vk1 * 2) ^ ((d1 & 7) << 4))) = vreg1[j];
    }
  };

  const int it0 = half * 16;
  load_g(it0);
  write_lds(0);

  for (int i = 0; i < 16; i++) {
    const int buf = i & 1;
    __syncthreads();                 // publishes write_lds(i) from all waves
    if (i + 1 < 16) load_g(it0 + i + 1); // next tile's loads fly during compute

    const unsigned char* ks = smem + buf * 8192;
    const unsigned char* vt = smem + 16384 + buf * 8192;

    // --- S^T = K @ Q^T : s[n][r] = S[kv = n*16+lg*4+r][q = lr] ---
    f32x4 s[4] = {};
    __builtin_amdgcn_s_setprio(1);
#pragma unroll
    for (int kc = 0; kc < 2; kc++) {
#pragma unroll
      for (int n = 0; n < 4; n++) {
        bf16x8 bk = *(const bf16x8*)(ks + (n * 16 + lr) * 128 +
                                     ((kc * 64 + lg * 16) ^ ((lr & 7) << 4)));
        s[n] = __builtin_amdgcn_mfma_f32_16x16x32_bf16(bk, aq[kc], s[n], 0, 0, 0);
      }
    }
    __builtin_amdgcn_s_setprio(0);

    // --- in-lane online softmax with defer-max (T13, THR=8) ---
    float pmax = -1e30f;
#pragma unroll
    for (int n = 0; n < 4; n++)
#pragma unroll
      for (int r = 0; r < 4; r++) pmax = fmaxf(pmax, s[n][r]);
    pmax = fmaxf(pmax, __shfl_xor(pmax, 16));
    pmax = fmaxf(pmax, __shfl_xor(pmax, 32));
    if (!__all(pmax <= m_run + 8.0f)) {
      float mnew = fmaxf(m_run, pmax);
      float scale = __expf(m_run - mnew);
      l_run *= scale;
#pragma unroll
      for (int n = 0; n < 4; n++)
#pragma unroll
        for (int r = 0; r < 4; r++) o[n][r] *= scale;
      m_run = mnew;
    }
    float rs = 0.f;
#pragma unroll
    for (int n = 0; n < 4; n++)
#pragma unroll
      for (int r = 0; r < 4; r++) {
        float e = __expf(s[n][r] - m_run);
        s[n][r] = e;
        rs += e;
      }
    rs += __shfl_xor(rs, 16);
    rs += __shfl_xor(rs, 32);
    l_run += rs;

    // --- PV from registers: o[n] += V^T(A) x P^T(B), 16x16x16 MFMA ---
    short4v pb[4];
#pragma unroll
    for (int n = 0; n < 4; n++) {
      bf16x4 t;
#pragma unroll
      for (int r = 0; r < 4; r++) t[r] = (bf16_t)s[n][r];
      pb[n] = __builtin_bit_cast(short4v, t);
    }
    __builtin_amdgcn_s_setprio(1);
#pragma unroll
    for (int n = 0; n < 4; n++) {
#pragma unroll
      for (int c2 = 0; c2 < 4; c2++) {
        bf16x4 bvh = *(const bf16x4*)(vt + (n * 16 + lr) * 128 +
                                      ((c2 * 32 + lg * 8) ^ ((lr & 7) << 4)));
        o[n] = __builtin_amdgcn_mfma_f32_16x16x16bf16_1k(
            __builtin_bit_cast(short4v, bvh), pb[c2], o[n], 0, 0, 0);
      }
    }
    __builtin_amdgcn_s_setprio(0);

    // consume in-flight loads into the other buffer
    if (i + 1 < 16) write_lds(buf ^ 1);
  }

  // --- write own partial: O^T in lane-order (coalesced), m/l per q-row ---
  float* ob = Opart + (size_t)pidx * 4096;
#pragma unroll
  for (int n = 0; n < 4; n++)
    *(f32x4*)(ob + ((w * 4 + n) * 64 + l) * 4) = o[n];
  if (lg == 0) {
    mlpart[(size_t)pidx * 128 + (w * 16 + lr) * 2 + 0] = m_run;
    mlpart[(size_t)pidx * 128 + (w * 16 + lr) * 2 + 1] = l_run;
  }

  // --- last-block-combines protocol (deterministic: role-indexed by half) ---
  __threadfence();                       // release own partial (device scope)
  __syncthreads();
  volatile int* shflag = (volatile int*)smem;   // LDS dead after loop
  if (tid == 0) shflag[0] = atomicAdd(&flags[gid], 1);
  __syncthreads();
  if (shflag[0] == 0) return;            // first finisher exits
  __threadfence();                       // acquire partner's partial

  const int partner = gid * 2 + (half ^ 1);
  float mO = mlpart[(size_t)partner * 128 + (w * 16 + lr) * 2 + 0];
  float lO = mlpart[(size_t)partner * 128 + (w * 16 + lr) * 2 + 1];
  float m = fmaxf(m_run, mO);
  float fM = __expf(m_run - m), fO = __expf(mO - m);
  // fixed evaluation order: A = half0 term, B = half1 term
  float lA = (half == 0) ? l_run * fM : lO * fO;
  float lB = (half == 0) ? lO * fO : l_run * fM;
  float inv = 1.0f / ((lA + lB) * 8.0f);     // /sqrt(DH) applied after softmax
  float gM = (half == 0) ? fM : fO;          // unused-order guard (kept symmetric)
  (void)gM;

  const float* obp = Opart + (size_t)partner * 4096;
  const int b = bh >> 3, h = bh & 7;
  const int t = qr0 + lr;
  size_t rowbase = ((size_t)b * SS + t) * 512 + h * 64;
#pragma unroll
  for (int n = 0; n < 4; n++) {
    f32x4 po = *(const f32x4*)(obp + ((w * 4 + n) * 64 + l) * 4);
    bf16x4 ov;
#pragma unroll
    for (int r = 0; r < 4; r++) {
      float a = (half == 0) ? o[n][r] * fM : po[r] * fO;
      float bt = (half == 0) ? po[r] * fO : o[n][r] * fM;
      ov[r] = (bf16_t)((a + bt) * inv);
    }
    *(bf16x4*)(&ctx[rowbase + n * 16 + lg * 4]) = ov;
  }
}

// ---------------- launcher ----------------
extern "C" void kernel_launch(void* const* d_in, const int* in_sizes, int n_in,
                              void* d_out, int out_size, void* d_ws, size_t ws_size,
                              hipStream_t stream) {
  const float* q  = (const float*)d_in[0];
  const float* k  = (const float*)d_in[1];
  const float* v  = (const float*)d_in[2];
  const float* Wq = (const float*)d_in[3];
  const float* bq = (const float*)d_in[4];
  const float* Wk = (const float*)d_in[5];
  const float* bk = (const float*)d_in[6];
  const float* Wv = (const float*)d_in[7];
  const float* bv = (const float*)d_in[8];
  const float* Wo = (const float*)d_in[9];
  const float* bo = (const float*)d_in[10];

  const size_t NQKV = (size_t)4096 * 512;   // 2,097,152 elems per tensor
  const size_t NW = (size_t)512 * 512;

  // ws layout (bf16 elems): [wt 4NW][proj 3NQKV][ctx NQKV][qkvb 3NQKV ...]
  // Opart/mlpart/flags overlap qkvb (dead after the QKV GEMM) + ~4.5MB beyond.
  bf16_t* ws   = (bf16_t*)d_ws;
  bf16_t* wt   = ws;                 // 2 MB
  bf16_t* proj = wt + 4 * NW;        // 12 MB
  bf16_t* ctx  = proj + 3 * NQKV;    // 4 MB
  bf16_t* qkvb = ctx + NQKV;         // 12 MB (dead after QKV GEMM)
  float* Opart  = (float*)qkvb;      // 16 MB  (1024 partials x 4096 f32)
  float* mlpart = Opart + (size_t)1024 * 4096;  // 0.5 MB
  int*   flags  = (int*)(mlpart + (size_t)1024 * 128);  // 2 KB

  // 0. zero the combine flags (graph-capture-safe, stream-ordered)
  hipMemsetAsync(flags, 0, 512 * sizeof(int), stream);
  // 1. cast q,k,v -> bf16 (z=0..2) + transpose+cast weights (z=3)
  prep<<<dim3(1024, 1, 4), 256, 0, stream>>>(q, k, v, Wq, Wk, Wv, Wo, qkvb, wt, (int)NQKV);
  // 2. fused QKV projections (z-batched)
  gemm_bt<bf16_t><<<dim3(4, 32, 3), 256, 0, stream>>>(
      qkvb, wt, bq, bk, bv, proj, 4096, 512, 512, (long)NQKV, (long)NW, (long)NQKV);
  // 3. flash attention, KV-split x2 (1024 blocks, XCD-affine) + fused combine
  attn_flash<<<1024, 256, 0, stream>>>(proj, proj + NQKV, proj + 2 * NQKV,
                                       Opart, mlpart, flags, ctx);
  // 4. output projection (f32 out)
  gemm_bt<float><<<dim3(4, 32, 1), 256, 0, stream>>>(
      ctx, wt + 3 * NW, bo, bo, bo, (float*)d_out, 4096, 512, 512, 0, 0, 0);
}

// Round 7
// 90.469 us; speedup vs baseline: 2.6694x; 2.6694x over previous
//
#include <hip/hip_runtime.h>
#include <hip/hip_bf16.h>

typedef __bf16 bf16_t;
typedef __bf16 bf16x8 __attribute__((ext_vector_type(8)));
typedef __bf16 bf16x4 __attribute__((ext_vector_type(4)));
typedef short short4v __attribute__((ext_vector_type(4)));
typedef float f32x4 __attribute__((ext_vector_type(4)));

static_assert(sizeof(bf16x8) == 16, "bf16x8 must be 16B");

// Problem constants
#define BB 2
#define SS 2048
#define DD 512
#define HH 8
#define DH 64
// HID == 512; head block = contiguous [2048,64] at (b*8+h)*131072

// ------------- prep: z=0..2 cast q/k/v f32->bf16; z=3 transpose+cast weights -------------
__global__ void prep(const float* __restrict__ q, const float* __restrict__ k,
                     const float* __restrict__ v, const float* __restrict__ w0,
                     const float* __restrict__ w1, const float* __restrict__ w2,
                     const float* __restrict__ w3, bf16_t* __restrict__ qkvb,
                     bf16_t* __restrict__ wt, int n) {
  const int tid = threadIdx.x;
  if (blockIdx.z < 3) {
    const float* src = (blockIdx.z == 0) ? q : (blockIdx.z == 1) ? k : v;
    bf16_t* out = qkvb + (size_t)blockIdx.z * n;
    int i = (blockIdx.x * 256 + tid) * 8;
    if (i >= n) return;
    const float4* s4 = (const float4*)(src + i);
    float4 a = s4[0], b = s4[1];
    bf16x8 o;
    o[0] = (bf16_t)a.x; o[1] = (bf16_t)a.y; o[2] = (bf16_t)a.z; o[3] = (bf16_t)a.w;
    o[4] = (bf16_t)b.x; o[5] = (bf16_t)b.y; o[6] = (bf16_t)b.z; o[7] = (bf16_t)b.w;
    *(bf16x8*)(out + i) = o;
  } else {
    // transpose+cast: Wt[nn][kk] = (bf16)W[kk][nn]
    __shared__ float tile[32][33];
    const int x = blockIdx.x;                  // 0..1023
    const int wsel = x >> 8;
    const int nb = ((x >> 4) & 15) * 32, kb = (x & 15) * 32;
    const int tx = tid & 31, ty = tid >> 5;    // (32,8)
    const float* W = (wsel == 0) ? w0 : (wsel == 1) ? w1 : (wsel == 2) ? w2 : w3;
    bf16_t* out = wt + (size_t)wsel * 512 * 512;
#pragma unroll
    for (int i = 0; i < 4; i++)
      tile[ty + i * 8][tx] = W[(size_t)(kb + ty + i * 8) * 512 + nb + tx];
    __syncthreads();
#pragma unroll
    for (int i = 0; i < 4; i++)
      out[(size_t)(nb + ty + i * 8) * 512 + kb + tx] = (bf16_t)tile[tx][ty + i * 8];
  }
}

// ------------- GEMM: C[M,N] = A[M,K] @ Bt[N,K]^T + bias[N] -------------
// 128x128 tile, BK=64, 256 thr (4 waves 2x2), global_load_lds(16B), dbuf LDS.
template <typename OutT>
__global__ __launch_bounds__(256) void gemm_bt(
    const bf16_t* __restrict__ Abase, const bf16_t* __restrict__ Btbase,
    const float* __restrict__ bias0, const float* __restrict__ bias1,
    const float* __restrict__ bias2, OutT* __restrict__ Cbase,
    int M, int N, int K, long Az, long Bz, long Cz) {
  const bf16_t* A  = Abase + (size_t)blockIdx.z * Az;
  const bf16_t* Bt = Btbase + (size_t)blockIdx.z * Bz;
  const float* bias = (blockIdx.z == 0) ? bias0 : (blockIdx.z == 1) ? bias1 : bias2;
  OutT* C = Cbase + (size_t)blockIdx.z * Cz;

  __shared__ bf16_t As[2][128 * 64];
  __shared__ bf16_t Bs[2][128 * 64];

  const int tid = threadIdx.x, w = tid >> 6, l = tid & 63;
  const int bm = blockIdx.y, bn = blockIdx.x;
  const int wm = (w >> 1) * 64, wn = (w & 1) * 64;
  const int lr = l & 15, lg = l >> 4;

  f32x4 acc[4][4] = {};

  auto stage = [&](int buf, int kt) {
#pragma unroll
    for (int j = 0; j < 4; j++) {
      int lin = (j * 4 + w) * 64 + l;       // 16B-chunk index 0..1023
      int row = lin >> 3, cc = lin & 7;
      const bf16_t* g = A + (size_t)(bm * 128 + row) * K + kt * 64 + cc * 8;
      __builtin_amdgcn_global_load_lds(
          (const __attribute__((address_space(1))) void*)g,
          (__attribute__((address_space(3))) void*)(&As[buf][(j * 4 + w) * 512]), 16, 0, 0);
    }
#pragma unroll
    for (int j = 0; j < 4; j++) {
      int lin = (j * 4 + w) * 64 + l;
      int row = lin >> 3, cc = lin & 7;
      const bf16_t* g = Bt + (size_t)(bn * 128 + row) * K + kt * 64 + cc * 8;
      __builtin_amdgcn_global_load_lds(
          (const __attribute__((address_space(1))) void*)g,
          (__attribute__((address_space(3))) void*)(&Bs[buf][(j * 4 + w) * 512]), 16, 0, 0);
    }
  };

  stage(0, 0);
  const int KT = K >> 6;
  for (int kt = 0; kt < KT; kt++) {
    __syncthreads();                         // drains vmcnt -> buf[kt&1] ready
    if (kt + 1 < KT) stage((kt + 1) & 1, kt + 1);
    const bf16_t* as = As[kt & 1];
    const bf16_t* bs = Bs[kt & 1];
#pragma unroll
    for (int kc = 0; kc < 2; kc++) {
      bf16x8 a[4], b[4];
#pragma unroll
      for (int i = 0; i < 4; i++)
        a[i] = *(const bf16x8*)(as + (wm + i * 16 + lr) * 64 + kc * 32 + lg * 8);
#pragma unroll
      for (int i = 0; i < 4; i++)
        b[i] = *(const bf16x8*)(bs + (wn + i * 16 + lr) * 64 + kc * 32 + lg * 8);
#pragma unroll
      for (int i = 0; i < 4; i++)
#pragma unroll
        for (int j = 0; j < 4; j++)
          acc[i][j] = __builtin_amdgcn_mfma_f32_16x16x32_bf16(a[i], b[j], acc[i][j], 0, 0, 0);
    }
  }

  // epilogue: C row = (lane>>4)*4+reg, col = lane&15 (verified m89/m91 layout)
  const int row0 = bm * 128 + wm, col0 = bn * 128 + wn;
#pragma unroll
  for (int j = 0; j < 4; j++) {
    int col = col0 + j * 16 + lr;
    float bv = bias[col];
#pragma unroll
    for (int i = 0; i < 4; i++) {
      int row = row0 + i * 16 + lg * 4;
#pragma unroll
      for (int r = 0; r < 4; r++) {
        float vv = acc[i][j][r] + bv;
        C[(size_t)(row + r) * N + col] = (OutT)vv;
      }
    }
  }
}

// ------------- flash attention, KV-split x2 -------------
// grid 1024 (1D): id bits -> bh low3 (XCD-affinity), bh hi, qt, half.
// Each block: QBLK=64 (4 waves x 16 q-rows), 16 KV-tiles (half the range).
// K: staged via global_load_lds from PRE-SWIZZLED global source into linear
//    LDS dest; read with XOR-swizzle (byte ^= (row&7)<<4) — layout identical
//    to R5's passed kernel.
// V: reg-roundtrip staging, XOR-swizzled V^T writes + swizzled b64 reads
//    (verbatim R5, passed). PV from registers via 16x16x16 MFMA, O^T accum.
// Swapped QK^T; in-lane online softmax with defer-max (T13).
__global__ __launch_bounds__(256) void attn_flash(const bf16_t* __restrict__ qp,
                                                  const bf16_t* __restrict__ kp,
                                                  const bf16_t* __restrict__ vp,
                                                  float* __restrict__ Opart,
                                                  float* __restrict__ mlpart) {
  const int id = blockIdx.x;
  const int bh = (id & 7) | (((id >> 3) & 1) << 3);  // blocks of one head share an XCD
  const int qt = (id >> 4) & 31;
  const int half = id >> 9;
  const int pidx = (((qt << 4) | bh) << 1) + half;

  const int tid = threadIdx.x, w = tid >> 6, l = tid & 63;
  const int lr = l & 15, lg = l >> 4;
  const size_t hb = (size_t)bh * (SS * DH);        // contiguous [2048,64] head block
  const bf16_t* Q = qp + hb;
  const bf16_t* Kh = kp + hb;
  const bf16_t* Vh = vp + hb;

  __shared__ __align__(16) bf16_t KsL[2][4096];    // [kv][64d] swizzled rows, 2x8KB
  __shared__ __align__(16) bf16_t VtL[2][4096];    // [d][64kv] swizzled rows, 2x8KB

  const int qr0 = qt * 64 + w * 16;

  // Q fragment (B-operand of QK^T: col=lr, k=lg*8+j), held for the whole kernel
  bf16x8 aq[2];
#pragma unroll
  for (int kc = 0; kc < 2; kc++)
    aq[kc] = *(const bf16x8*)(Q + (size_t)(qr0 + lr) * DH + kc * 32 + lg * 8);

  f32x4 o[4] = {};                    // O^T[d = n*16+lg*4+r][q = lr]
  float m_run = -1e30f, l_run = 0.f;  // per-lane scalars (row q = lr)

  // --- K staging source (pre-swizzled; chunk c = w*64+l -> row c>>3, slot (c&7)*16B,
  //     source col = slot ^ ((row&7)<<4); row&7 == l>>3) ---
  const int krow = (w << 3) + (l >> 3);
  const int kcol = ((l & 7) ^ (l >> 3)) << 3;               // element offset
  const bf16_t* ks_it = Kh + (size_t)(half * 16) * 4096 + krow * 64 + kcol;

  auto stage_k = [&](int buf, const bf16_t* ks) {
    char* kb = (char*)&KsL[buf][0];
    __builtin_amdgcn_global_load_lds((const __attribute__((address_space(1))) void*)ks,
        (__attribute__((address_space(3))) void*)(kb + (w << 10)), 16, 0, 0);
    __builtin_amdgcn_global_load_lds((const __attribute__((address_space(1))) void*)(ks + 2048),
        (__attribute__((address_space(3))) void*)(kb + 4096 + (w << 10)), 16, 0, 0);
  };

  // --- V staging (reg roundtrip, R5-verbatim): thread (w,l) loads V[kv=l][w*8..] and
  //     V[kv=l][32+w*8..]; writes V^T swizzled: vt[d*128 + ((kv*2) ^ ((d&7)<<4))] ---
  const int vk0 = l, vd0 = w;
  const int vd1 = 4 + w;
  bf16x8 vreg0, vreg1;
  auto load_v = [&](int it) {
    const size_t kv0 = (size_t)it * 64;
    vreg0 = *(const bf16x8*)(Vh + (kv0 + vk0) * DH + vd0 * 8);
    vreg1 = *(const bf16x8*)(Vh + (kv0 + vk0) * DH + vd1 * 8);
  };
  auto write_v = [&](int buf) {
    char* vt = (char*)&VtL[buf][0];
#pragma unroll
    for (int j = 0; j < 8; j++) {
      int d0 = vd0 * 8 + j;                       // d0&7 == j
      *(bf16_t*)(vt + d0 * 128 + ((vk0 * 2) ^ (j << 4))) = vreg0[j];
    }
#pragma unroll
    for (int j = 0; j < 8; j++) {
      int d1 = vd1 * 8 + j;                       // d1&7 == j
      *(bf16_t*)(vt + d1 * 128 + ((vk0 * 2) ^ (j << 4))) = vreg1[j];
    }
  };

  stage_k(0, ks_it);
  load_v(half * 16);
  write_v(0);

  for (int i = 0; i < 16; i++) {
    const int buf = i & 1;
    __syncthreads();                 // drains K gload_lds; publishes V writes
    if (i + 1 < 16) {
      ks_it += 4096;
      stage_k(buf ^ 1, ks_it);       // async into other buffer
      load_v(half * 16 + i + 1);     // in flight during compute (T14)
    }

    // --- S^T = K @ Q^T : s[n][r] = S[kv=n*16+lg*4+r][q=lr] ---
    const char* ksb = (const char*)&KsL[buf][0];
    f32x4 s[4] = {};
    __builtin_amdgcn_s_setprio(1);
#pragma unroll
    for (int kc = 0; kc < 2; kc++) {
#pragma unroll
      for (int n = 0; n < 4; n++) {
        bf16x8 bk = *(const bf16x8*)(ksb + (n * 16 + lr) * 128 +
                                     ((kc * 64 + lg * 16) ^ ((lr & 7) << 4)));
        s[n] = __builtin_amdgcn_mfma_f32_16x16x32_bf16(bk, aq[kc], s[n], 0, 0, 0);
      }
    }
    __builtin_amdgcn_s_setprio(0);

    // --- in-lane online softmax with defer-max (T13, THR=8) ---
    float pmax = -1e30f;
#pragma unroll
    for (int n = 0; n < 4; n++)
#pragma unroll
      for (int r = 0; r < 4; r++) pmax = fmaxf(pmax, s[n][r]);
    pmax = fmaxf(pmax, __shfl_xor(pmax, 16));
    pmax = fmaxf(pmax, __shfl_xor(pmax, 32));
    if (!__all(pmax <= m_run + 8.0f)) {
      float mnew = fmaxf(m_run, pmax);
      float scale = __expf(m_run - mnew);   // per-lane uniform (O^T layout)
      l_run *= scale;
#pragma unroll
      for (int n = 0; n < 4; n++)
#pragma unroll
        for (int r = 0; r < 4; r++) o[n][r] *= scale;
      m_run = mnew;
    }
    float rs = 0.f;
#pragma unroll
    for (int n = 0; n < 4; n++)
#pragma unroll
      for (int r = 0; r < 4; r++) {
        float e = __expf(s[n][r] - m_run);
        s[n][r] = e;
        rs += e;
      }
    rs += __shfl_xor(rs, 16);
    rs += __shfl_xor(rs, 32);
    l_run += rs;

    // --- PV from registers: o[n] += V^T(A) x P^T(B), 16x16x16 MFMA (R5 path) ---
    short4v pb[4];
#pragma unroll
    for (int c2 = 0; c2 < 4; c2++) {
      bf16x4 t;
#pragma unroll
      for (int r = 0; r < 4; r++) t[r] = (bf16_t)s[c2][r];
      pb[c2] = __builtin_bit_cast(short4v, t);
    }
    const char* vtb = (const char*)&VtL[buf][0];
    __builtin_amdgcn_s_setprio(1);
#pragma unroll
    for (int n = 0; n < 4; n++) {
#pragma unroll
      for (int c2 = 0; c2 < 4; c2++) {
        bf16x4 bvh = *(const bf16x4*)(vtb + (n * 16 + lr) * 128 +
                                      ((c2 * 32 + lg * 8) ^ ((lr & 7) << 4)));
        o[n] = __builtin_amdgcn_mfma_f32_16x16x16bf16_1k(
            __builtin_bit_cast(short4v, bvh), pb[c2], o[n], 0, 0, 0);
      }
    }
    __builtin_amdgcn_s_setprio(0);

    // consume in-flight V loads into the other buffer
    if (i + 1 < 16) write_v(buf ^ 1);
  }

  // --- write partials: O^T in lane-order (coalesced), m/l per q-row ---
  float* ob = Opart + (size_t)pidx * 4096;
#pragma unroll
  for (int n = 0; n < 4; n++)
    *(f32x4*)(ob + ((w * 4 + n) * 64 + l) * 4) = o[n];
  if (lg == 0) {
    mlpart[(size_t)pidx * 128 + (w * 16 + lr) * 2 + 0] = m_run;
    mlpart[(size_t)pidx * 128 + (w * 16 + lr) * 2 + 1] = l_run;
  }
}

// ------------- combine the two KV-halves -> ctx (bf16)  [R4-verbatim, passed] -------------
__global__ __launch_bounds__(256) void attn_combine(const float* __restrict__ Opart,
                                                    const float* __restrict__ mlpart,
                                                    bf16_t* __restrict__ ctx) {
  const int id = blockIdx.x;                 // 512 = qt*16 + bh
  const int qt = id >> 4, bh = id & 15;
  const int t = threadIdx.x, w = t >> 6, l = t & 63;
  const int lr = l & 15, lg = l >> 4;
  const int p0 = id * 2, p1 = id * 2 + 1;
  const int q = w * 16 + lr;

  float m1 = mlpart[(size_t)p0 * 128 + q * 2 + 0];
  float l1 = mlpart[(size_t)p0 * 128 + q * 2 + 1];
  float m2 = mlpart[(size_t)p1 * 128 + q * 2 + 0];
  float l2 = mlpart[(size_t)p1 * 128 + q * 2 + 1];
  float m = fmaxf(m1, m2);
  float e1 = __expf(m1 - m), e2 = __expf(m2 - m);
  float denom = (l1 * e1 + l2 * e2) * 8.0f;     // /sqrt(DH) after softmax
  float f1 = e1 / denom, f2 = e2 / denom;

  const int b = bh >> 3, h = bh & 7;
  const int trow = qt * 64 + q;
  size_t rowbase = ((size_t)b * SS + trow) * 512 + h * 64;

  const float* oa = Opart + (size_t)p0 * 4096;
  const float* obp = Opart + (size_t)p1 * 4096;
#pragma unroll
  for (int n = 0; n < 4; n++) {
    f32x4 a = *(const f32x4*)(oa + ((w * 4 + n) * 64 + l) * 4);
    f32x4 b2 = *(const f32x4*)(obp + ((w * 4 + n) * 64 + l) * 4);
    bf16x4 ov;
#pragma unroll
    for (int r = 0; r < 4; r++) ov[r] = (bf16_t)(a[r] * f1 + b2[r] * f2);
    *(bf16x4*)(&ctx[rowbase + n * 16 + lg * 4]) = ov;
  }
}

// ---------------- launcher ----------------
extern "C" void kernel_launch(void* const* d_in, const int* in_sizes, int n_in,
                              void* d_out, int out_size, void* d_ws, size_t ws_size,
                              hipStream_t stream) {
  const float* q  = (const float*)d_in[0];
  const float* k  = (const float*)d_in[1];
  const float* v  = (const float*)d_in[2];
  const float* Wq = (const float*)d_in[3];
  const float* bq = (const float*)d_in[4];
  const float* Wk = (const float*)d_in[5];
  const float* bk = (const float*)d_in[6];
  const float* Wv = (const float*)d_in[7];
  const float* bv = (const float*)d_in[8];
  const float* Wo = (const float*)d_in[9];
  const float* bo = (const float*)d_in[10];

  const size_t NQKV = (size_t)4096 * 512;   // 2,097,152 elems per tensor
  const size_t NW = (size_t)512 * 512;

  // ws layout (bf16 elems): [wt 4NW][proj 3NQKV][ctx NQKV][qkvb 3NQKV ...]
  // Opart/mlpart overlap qkvb (dead after the QKV GEMM) + ~4.5MB beyond.
  bf16_t* ws   = (bf16_t*)d_ws;
  bf16_t* wt   = ws;                 // 2 MB
  bf16_t* proj = wt + 4 * NW;        // 12 MB
  bf16_t* ctx  = proj + 3 * NQKV;    // 4 MB
  bf16_t* qkvb = ctx + NQKV;         // 12 MB (dead after QKV GEMM)
  float* Opart  = (float*)qkvb;      // 16 MB  (1024 partials x 4096 f32)
  float* mlpart = Opart + (size_t)1024 * 4096;  // 0.5 MB

  // 1. cast q,k,v -> bf16 (z=0..2) + transpose+cast weights (z=3)
  prep<<<dim3(1024, 1, 4), 256, 0, stream>>>(q, k, v, Wq, Wk, Wv, Wo, qkvb, wt, (int)NQKV);
  // 2. fused QKV projections (z-batched)
  gemm_bt<bf16_t><<<dim3(4, 32, 3), 256, 0, stream>>>(
      qkvb, wt, bq, bk, bv, proj, 4096, 512, 512, (long)NQKV, (long)NW, (long)NQKV);
  // 3. flash attention, KV-split x2 (1024 blocks, XCD-affine)
  attn_flash<<<1024, 256, 0, stream>>>(proj, proj + NQKV, proj + 2 * NQKV, Opart, mlpart);
  // 4. combine halves -> ctx (kernel boundary = free device-wide release/acquire)
  attn_combine<<<512, 256, 0, stream>>>(Opart, mlpart, ctx);
  // 5. output projection (f32 out)
  gemm_bt<float><<<dim3(4, 32, 1), 256, 0, stream>>>(
      ctx, wt + 3 * NW, bo, bo, bo, (float*)d_out, 4096, 512, 512, 0, 0, 0);
}

// Round 8
// 90.415 us; speedup vs baseline: 2.6710x; 1.0006x over previous
//
#include <hip/hip_runtime.h>
#include <hip/hip_bf16.h>

typedef __bf16 bf16_t;
typedef __bf16 bf16x8 __attribute__((ext_vector_type(8)));
typedef __bf16 bf16x4 __attribute__((ext_vector_type(4)));
typedef short short4v __attribute__((ext_vector_type(4)));
typedef float f32x4 __attribute__((ext_vector_type(4)));

static_assert(sizeof(bf16x8) == 16, "bf16x8 must be 16B");

// Problem constants
#define BB 2
#define SS 2048
#define DD 512
#define HH 8
#define DH 64
// HID == 512; head block = contiguous [2048,64] at (b*8+h)*131072

// ------------- prep: z=0..2 cast q/k/v f32->bf16; z=3 transpose+cast weights -------------
__global__ void prep(const float* __restrict__ q, const float* __restrict__ k,
                     const float* __restrict__ v, const float* __restrict__ w0,
                     const float* __restrict__ w1, const float* __restrict__ w2,
                     const float* __restrict__ w3, bf16_t* __restrict__ qkvb,
                     bf16_t* __restrict__ wt, int n) {
  const int tid = threadIdx.x;
  if (blockIdx.z < 3) {
    const float* src = (blockIdx.z == 0) ? q : (blockIdx.z == 1) ? k : v;
    bf16_t* out = qkvb + (size_t)blockIdx.z * n;
    int i = (blockIdx.x * 256 + tid) * 8;
    if (i >= n) return;
    const float4* s4 = (const float4*)(src + i);
    float4 a = s4[0], b = s4[1];
    bf16x8 o;
    o[0] = (bf16_t)a.x; o[1] = (bf16_t)a.y; o[2] = (bf16_t)a.z; o[3] = (bf16_t)a.w;
    o[4] = (bf16_t)b.x; o[5] = (bf16_t)b.y; o[6] = (bf16_t)b.z; o[7] = (bf16_t)b.w;
    *(bf16x8*)(out + i) = o;
  } else {
    // transpose+cast: Wt[nn][kk] = (bf16)W[kk][nn]
    __shared__ float tile[32][33];
    const int x = blockIdx.x;                  // 0..1023
    const int wsel = x >> 8;
    const int nb = ((x >> 4) & 15) * 32, kb = (x & 15) * 32;
    const int tx = tid & 31, ty = tid >> 5;    // (32,8)
    const float* W = (wsel == 0) ? w0 : (wsel == 1) ? w1 : (wsel == 2) ? w2 : w3;
    bf16_t* out = wt + (size_t)wsel * 512 * 512;
#pragma unroll
    for (int i = 0; i < 4; i++)
      tile[ty + i * 8][tx] = W[(size_t)(kb + ty + i * 8) * 512 + nb + tx];
    __syncthreads();
#pragma unroll
    for (int i = 0; i < 4; i++)
      out[(size_t)(nb + ty + i * 8) * 512 + kb + tx] = (bf16_t)tile[tx][ty + i * 8];
  }
}

// ------------- GEMM: C[M,N] = A[M,K] @ Bt[N,K]^T + bias[N] -------------
// Templated tile: BM x BN, BK=64, 256 thr, 4 waves in fixed 2x2 grid of
// WM x WN sub-tiles (BM == 2*WM, BN == 2*WN). global_load_lds(16B), dbuf LDS.
// Derived: FM=WM/16 M-frags, FN=WN/16 N-frags per wave; A stage = BM/32
// chunks/thread, B stage = BN/32.
template <int BM, int BN, int WM, int WN, typename OutT>
__global__ __launch_bounds__(256) void gemm2(
    const bf16_t* __restrict__ Abase, const bf16_t* __restrict__ Btbase,
    const float* __restrict__ bias0, const float* __restrict__ bias1,
    const float* __restrict__ bias2, OutT* __restrict__ Cbase,
    int M, int N, int K, long Az, long Bz, long Cz) {
  static_assert(BM == 2 * WM && BN == 2 * WN, "2x2 wave grid");
  constexpr int FM = WM / 16, FN = WN / 16;
  constexpr int AJ = BM / 32, BJ = BN / 32;

  const bf16_t* A  = Abase + (size_t)blockIdx.z * Az;
  const bf16_t* Bt = Btbase + (size_t)blockIdx.z * Bz;
  const float* bias = (blockIdx.z == 0) ? bias0 : (blockIdx.z == 1) ? bias1 : bias2;
  OutT* C = Cbase + (size_t)blockIdx.z * Cz;

  __shared__ bf16_t As[2][BM * 64];
  __shared__ bf16_t Bs[2][BN * 64];

  const int tid = threadIdx.x, w = tid >> 6, l = tid & 63;
  const int bm = blockIdx.y, bn = blockIdx.x;
  const int wm0 = (w >> 1) * WM, wn0 = (w & 1) * WN;
  const int lr = l & 15, lg = l >> 4;

  f32x4 acc[FM][FN] = {};

  auto stage = [&](int buf, int kt) {
#pragma unroll
    for (int j = 0; j < AJ; j++) {
      int lin = j * 256 + tid;              // 16B-chunk index
      int row = lin >> 3, cc = lin & 7;
      const bf16_t* g = A + (size_t)(bm * BM + row) * K + kt * 64 + cc * 8;
      __builtin_amdgcn_global_load_lds(
          (const __attribute__((address_space(1))) void*)g,
          (__attribute__((address_space(3))) void*)(&As[buf][(j * 256 + w * 64) * 8]), 16, 0, 0);
    }
#pragma unroll
    for (int j = 0; j < BJ; j++) {
      int lin = j * 256 + tid;
      int row = lin >> 3, cc = lin & 7;
      const bf16_t* g = Bt + (size_t)(bn * BN + row) * K + kt * 64 + cc * 8;
      __builtin_amdgcn_global_load_lds(
          (const __attribute__((address_space(1))) void*)g,
          (__attribute__((address_space(3))) void*)(&Bs[buf][(j * 256 + w * 64) * 8]), 16, 0, 0);
    }
  };

  stage(0, 0);
  const int KT = K >> 6;
  for (int kt = 0; kt < KT; kt++) {
    __syncthreads();                         // drains vmcnt -> buf[kt&1] ready
    if (kt + 1 < KT) stage((kt + 1) & 1, kt + 1);
    const bf16_t* as = As[kt & 1];
    const bf16_t* bs = Bs[kt & 1];
#pragma unroll
    for (int kc = 0; kc < 2; kc++) {
      bf16x8 a[FM], b[FN];
#pragma unroll
      for (int i = 0; i < FM; i++)
        a[i] = *(const bf16x8*)(as + (wm0 + i * 16 + lr) * 64 + kc * 32 + lg * 8);
#pragma unroll
      for (int j = 0; j < FN; j++)
        b[j] = *(const bf16x8*)(bs + (wn0 + j * 16 + lr) * 64 + kc * 32 + lg * 8);
#pragma unroll
      for (int i = 0; i < FM; i++)
#pragma unroll
        for (int j = 0; j < FN; j++)
          acc[i][j] = __builtin_amdgcn_mfma_f32_16x16x32_bf16(a[i], b[j], acc[i][j], 0, 0, 0);
    }
  }

  // epilogue: C row = (lane>>4)*4+reg, col = lane&15 (verified m89/m91 layout)
  const int row0 = bm * BM + wm0, col0 = bn * BN + wn0;
#pragma unroll
  for (int j = 0; j < FN; j++) {
    int col = col0 + j * 16 + lr;
    float bv = bias[col];
#pragma unroll
    for (int i = 0; i < FM; i++) {
      int row = row0 + i * 16 + lg * 4;
#pragma unroll
      for (int r = 0; r < 4; r++) {
        float vv = acc[i][j][r] + bv;
        C[(size_t)(row + r) * N + col] = (OutT)vv;
      }
    }
  }
}

// ------------- flash attention, KV-split x2 (R7-verbatim, passed) -------------
__global__ __launch_bounds__(256) void attn_flash(const bf16_t* __restrict__ qp,
                                                  const bf16_t* __restrict__ kp,
                                                  const bf16_t* __restrict__ vp,
                                                  float* __restrict__ Opart,
                                                  float* __restrict__ mlpart) {
  const int id = blockIdx.x;
  const int bh = (id & 7) | (((id >> 3) & 1) << 3);  // blocks of one head share an XCD
  const int qt = (id >> 4) & 31;
  const int half = id >> 9;
  const int pidx = (((qt << 4) | bh) << 1) + half;

  const int tid = threadIdx.x, w = tid >> 6, l = tid & 63;
  const int lr = l & 15, lg = l >> 4;
  const size_t hb = (size_t)bh * (SS * DH);        // contiguous [2048,64] head block
  const bf16_t* Q = qp + hb;
  const bf16_t* Kh = kp + hb;
  const bf16_t* Vh = vp + hb;

  __shared__ __align__(16) bf16_t KsL[2][4096];    // [kv][64d] swizzled rows, 2x8KB
  __shared__ __align__(16) bf16_t VtL[2][4096];    // [d][64kv] swizzled rows, 2x8KB

  const int qr0 = qt * 64 + w * 16;

  // Q fragment (B-operand of QK^T: col=lr, k=lg*8+j), held for the whole kernel
  bf16x8 aq[2];
#pragma unroll
  for (int kc = 0; kc < 2; kc++)
    aq[kc] = *(const bf16x8*)(Q + (size_t)(qr0 + lr) * DH + kc * 32 + lg * 8);

  f32x4 o[4] = {};                    // O^T[d = n*16+lg*4+r][q = lr]
  float m_run = -1e30f, l_run = 0.f;  // per-lane scalars (row q = lr)

  // --- K staging source (pre-swizzled; chunk c = w*64+l -> row c>>3, slot (c&7)*16B,
  //     source col = slot ^ ((row&7)<<4); row&7 == l>>3) ---
  const int krow = (w << 3) + (l >> 3);
  const int kcol = ((l & 7) ^ (l >> 3)) << 3;               // element offset
  const bf16_t* ks_it = Kh + (size_t)(half * 16) * 4096 + krow * 64 + kcol;

  auto stage_k = [&](int buf, const bf16_t* ks) {
    char* kb = (char*)&KsL[buf][0];
    __builtin_amdgcn_global_load_lds((const __attribute__((address_space(1))) void*)ks,
        (__attribute__((address_space(3))) void*)(kb + (w << 10)), 16, 0, 0);
    __builtin_amdgcn_global_load_lds((const __attribute__((address_space(1))) void*)(ks + 2048),
        (__attribute__((address_space(3))) void*)(kb + 4096 + (w << 10)), 16, 0, 0);
  };

  // --- V staging (reg roundtrip): thread (w,l) loads V[kv=l][w*8..] and
  //     V[kv=l][32+w*8..]; writes V^T swizzled: vt[d*128 + ((kv*2) ^ ((d&7)<<4))] ---
  const int vk0 = l, vd0 = w;
  const int vd1 = 4 + w;
  bf16x8 vreg0, vreg1;
  auto load_v = [&](int it) {
    const size_t kv0 = (size_t)it * 64;
    vreg0 = *(const bf16x8*)(Vh + (kv0 + vk0) * DH + vd0 * 8);
    vreg1 = *(const bf16x8*)(Vh + (kv0 + vk0) * DH + vd1 * 8);
  };
  auto write_v = [&](int buf) {
    char* vt = (char*)&VtL[buf][0];
#pragma unroll
    for (int j = 0; j < 8; j++) {
      int d0 = vd0 * 8 + j;                       // d0&7 == j
      *(bf16_t*)(vt + d0 * 128 + ((vk0 * 2) ^ (j << 4))) = vreg0[j];
    }
#pragma unroll
    for (int j = 0; j < 8; j++) {
      int d1 = vd1 * 8 + j;                       // d1&7 == j
      *(bf16_t*)(vt + d1 * 128 + ((vk0 * 2) ^ (j << 4))) = vreg1[j];
    }
  };

  stage_k(0, ks_it);
  load_v(half * 16);
  write_v(0);

  for (int i = 0; i < 16; i++) {
    const int buf = i & 1;
    __syncthreads();                 // drains K gload_lds; publishes V writes
    if (i + 1 < 16) {
      ks_it += 4096;
      stage_k(buf ^ 1, ks_it);       // async into other buffer
      load_v(half * 16 + i + 1);     // in flight during compute (T14)
    }

    // --- S^T = K @ Q^T : s[n][r] = S[kv=n*16+lg*4+r][q=lr] ---
    const char* ksb = (const char*)&KsL[buf][0];
    f32x4 s[4] = {};
    __builtin_amdgcn_s_setprio(1);
#pragma unroll
    for (int kc = 0; kc < 2; kc++) {
#pragma unroll
      for (int n = 0; n < 4; n++) {
        bf16x8 bk = *(const bf16x8*)(ksb + (n * 16 + lr) * 128 +
                                     ((kc * 64 + lg * 16) ^ ((lr & 7) << 4)));
        s[n] = __builtin_amdgcn_mfma_f32_16x16x32_bf16(bk, aq[kc], s[n], 0, 0, 0);
      }
    }
    __builtin_amdgcn_s_setprio(0);

    // --- in-lane online softmax with defer-max (T13, THR=8) ---
    float pmax = -1e30f;
#pragma unroll
    for (int n = 0; n < 4; n++)
#pragma unroll
      for (int r = 0; r < 4; r++) pmax = fmaxf(pmax, s[n][r]);
    pmax = fmaxf(pmax, __shfl_xor(pmax, 16));
    pmax = fmaxf(pmax, __shfl_xor(pmax, 32));
    if (!__all(pmax <= m_run + 8.0f)) {
      float mnew = fmaxf(m_run, pmax);
      float scale = __expf(m_run - mnew);   // per-lane uniform (O^T layout)
      l_run *= scale;
#pragma unroll
      for (int n = 0; n < 4; n++)
#pragma unroll
        for (int r = 0; r < 4; r++) o[n][r] *= scale;
      m_run = mnew;
    }
    float rs = 0.f;
#pragma unroll
    for (int n = 0; n < 4; n++)
#pragma unroll
      for (int r = 0; r < 4; r++) {
        float e = __expf(s[n][r] - m_run);
        s[n][r] = e;
        rs += e;
      }
    rs += __shfl_xor(rs, 16);
    rs += __shfl_xor(rs, 32);
    l_run += rs;

    // --- PV from registers: o[n] += V^T(A) x P^T(B), 16x16x16 MFMA ---
    short4v pb[4];
#pragma unroll
    for (int c2 = 0; c2 < 4; c2++) {
      bf16x4 t;
#pragma unroll
      for (int r = 0; r < 4; r++) t[r] = (bf16_t)s[c2][r];
      pb[c2] = __builtin_bit_cast(short4v, t);
    }
    const char* vtb = (const char*)&VtL[buf][0];
    __builtin_amdgcn_s_setprio(1);
#pragma unroll
    for (int n = 0; n < 4; n++) {
#pragma unroll
      for (int c2 = 0; c2 < 4; c2++) {
        bf16x4 bvh = *(const bf16x4*)(vtb + (n * 16 + lr) * 128 +
                                      ((c2 * 32 + lg * 8) ^ ((lr & 7) << 4)));
        o[n] = __builtin_amdgcn_mfma_f32_16x16x16bf16_1k(
            __builtin_bit_cast(short4v, bvh), pb[c2], o[n], 0, 0, 0);
      }
    }
    __builtin_amdgcn_s_setprio(0);

    // consume in-flight V loads into the other buffer
    if (i + 1 < 16) write_v(buf ^ 1);
  }

  // --- write partials: O^T in lane-order (coalesced), m/l per q-row ---
  float* ob = Opart + (size_t)pidx * 4096;
#pragma unroll
  for (int n = 0; n < 4; n++)
    *(f32x4*)(ob + ((w * 4 + n) * 64 + l) * 4) = o[n];
  if (lg == 0) {
    mlpart[(size_t)pidx * 128 + (w * 16 + lr) * 2 + 0] = m_run;
    mlpart[(size_t)pidx * 128 + (w * 16 + lr) * 2 + 1] = l_run;
  }
}

// ------------- combine the two KV-halves -> ctx (bf16)  [R4-verbatim, passed] -------------
__global__ __launch_bounds__(256) void attn_combine(const float* __restrict__ Opart,
                                                    const float* __restrict__ mlpart,
                                                    bf16_t* __restrict__ ctx) {
  const int id = blockIdx.x;                 // 512 = qt*16 + bh
  const int qt = id >> 4, bh = id & 15;
  const int t = threadIdx.x, w = t >> 6, l = t & 63;
  const int lr = l & 15, lg = l >> 4;
  const int p0 = id * 2, p1 = id * 2 + 1;
  const int q = w * 16 + lr;

  float m1 = mlpart[(size_t)p0 * 128 + q * 2 + 0];
  float l1 = mlpart[(size_t)p0 * 128 + q * 2 + 1];
  float m2 = mlpart[(size_t)p1 * 128 + q * 2 + 0];
  float l2 = mlpart[(size_t)p1 * 128 + q * 2 + 1];
  float m = fmaxf(m1, m2);
  float e1 = __expf(m1 - m), e2 = __expf(m2 - m);
  float denom = (l1 * e1 + l2 * e2) * 8.0f;     // /sqrt(DH) after softmax
  float f1 = e1 / denom, f2 = e2 / denom;

  const int b = bh >> 3, h = bh & 7;
  const int trow = qt * 64 + q;
  size_t rowbase = ((size_t)b * SS + trow) * 512 + h * 64;

  const float* oa = Opart + (size_t)p0 * 4096;
  const float* obp = Opart + (size_t)p1 * 4096;
#pragma unroll
  for (int n = 0; n < 4; n++) {
    f32x4 a = *(const f32x4*)(oa + ((w * 4 + n) * 64 + l) * 4);
    f32x4 b2 = *(const f32x4*)(obp + ((w * 4 + n) * 64 + l) * 4);
    bf16x4 ov;
#pragma unroll
    for (int r = 0; r < 4; r++) ov[r] = (bf16_t)(a[r] * f1 + b2[r] * f2);
    *(bf16x4*)(&ctx[rowbase + n * 16 + lg * 4]) = ov;
  }
}

// ---------------- launcher ----------------
extern "C" void kernel_launch(void* const* d_in, const int* in_sizes, int n_in,
                              void* d_out, int out_size, void* d_ws, size_t ws_size,
                              hipStream_t stream) {
  const float* q  = (const float*)d_in[0];
  const float* k  = (const float*)d_in[1];
  const float* v  = (const float*)d_in[2];
  const float* Wq = (const float*)d_in[3];
  const float* bq = (const float*)d_in[4];
  const float* Wk = (const float*)d_in[5];
  const float* bk = (const float*)d_in[6];
  const float* Wv = (const float*)d_in[7];
  const float* bv = (const float*)d_in[8];
  const float* Wo = (const float*)d_in[9];
  const float* bo = (const float*)d_in[10];

  const size_t NQKV = (size_t)4096 * 512;   // 2,097,152 elems per tensor
  const size_t NW = (size_t)512 * 512;

  // ws layout (bf16 elems): [wt 4NW][proj 3NQKV][ctx NQKV][qkvb 3NQKV ...]
  // Opart/mlpart overlap qkvb (dead after the QKV GEMM) + ~4.5MB beyond.
  bf16_t* ws   = (bf16_t*)d_ws;
  bf16_t* wt   = ws;                 // 2 MB
  bf16_t* proj = wt + 4 * NW;        // 12 MB
  bf16_t* ctx  = proj + 3 * NQKV;    // 4 MB
  bf16_t* qkvb = ctx + NQKV;         // 12 MB (dead after QKV GEMM)
  float* Opart  = (float*)qkvb;      // 16 MB  (1024 partials x 4096 f32)
  float* mlpart = Opart + (size_t)1024 * 4096;  // 0.5 MB

  // 1. cast q,k,v -> bf16 (z=0..2) + transpose+cast weights (z=3)
  prep<<<dim3(1024, 1, 4), 256, 0, stream>>>(q, k, v, Wq, Wk, Wv, Wo, qkvb, wt, (int)NQKV);
  // 2. fused QKV projections: 128x64 tiles -> 768 blocks = 3/CU (48KB LDS)
  gemm2<128, 64, 64, 32, bf16_t><<<dim3(8, 32, 3), 256, 0, stream>>>(
      qkvb, wt, bq, bk, bv, proj, 4096, 512, 512, (long)NQKV, (long)NW, (long)NQKV);
  // 3. flash attention, KV-split x2 (1024 blocks, XCD-affine)
  attn_flash<<<1024, 256, 0, stream>>>(proj, proj + NQKV, proj + 2 * NQKV, Opart, mlpart);
  // 4. combine halves -> ctx
  attn_combine<<<512, 256, 0, stream>>>(Opart, mlpart, ctx);
  // 5. output projection: 64x64 tiles -> 512 blocks = 2/CU (32KB LDS)
  gemm2<64, 64, 32, 32, float><<<dim3(8, 64, 1), 256, 0, stream>>>(
      ctx, wt + 3 * NW, bo, bo, bo, (float*)d_out, 4096, 512, 512, 0, 0, 0);
}